// Round 10
// baseline (290.404 us; speedup 1.0000x reference)
//
#include <hip/hip_runtime.h>
#include <hip/hip_bf16.h>

#define T_SEQ 80
#define TPAD  81
#define EMB   100
#define HU    128
#define G4    512
#define BR    16
#define THR   512
#define LOG2E 1.44269504f

typedef __attribute__((ext_vector_type(8))) short bfrag;
typedef __attribute__((ext_vector_type(4))) float f32x4;

// ws layout (bytes)
#define OFF_EW1P 0ull                       // 10000*512*2 = 10,240,000
#define OFF_U1T  10240000ull                // 131072
#define OFF_U2T  (OFF_U1T + 131072ull)
#define OFF_W2T  (OFF_U2T + 131072ull)

__device__ inline unsigned short f2bf(float x) {
    __hip_bfloat16 h = __float2bfloat16(x);
    unsigned short u; __builtin_memcpy(&u, &h, 2); return u;
}
__device__ inline float lo_bf(unsigned int d) {
    unsigned int v = d << 16; float f; __builtin_memcpy(&f, &v, 4); return f;
}
__device__ inline float hi_bf(unsigned int d) {
    unsigned int v = d & 0xffff0000u; float f; __builtin_memcpy(&f, &v, 4); return f;
}
__device__ inline unsigned int cvt_pk_bf16(float a, float b) {
    unsigned int d;
    asm("v_cvt_pk_bf16_f32 %0, %1, %2" : "=v"(d) : "v"(a), "v"(b));
    return d;   // lo = bf16(a), hi = bf16(b)
}
// gates on PRE-SCALED z: i/f/o columns scaled by -log2e, g columns by +2log2e
__device__ inline float sig_p(float zp) {
    return __builtin_amdgcn_rcpf(1.f + __builtin_amdgcn_exp2f(zp));
}
__device__ inline float tanh_p(float zp) {
    return 1.f - 2.f * __builtin_amdgcn_rcpf(1.f + __builtin_amdgcn_exp2f(zp));
}
__device__ inline float tanh_r(float x) {
    return 1.f - 2.f * __builtin_amdgcn_rcpf(1.f + __builtin_amdgcn_exp2f(2.f * LOG2E * x));
}
__device__ inline float sig_r(float x) {
    return __builtin_amdgcn_rcpf(1.f + __builtin_amdgcn_exp2f(-LOG2E * x));
}
// frag load from swizzled row-major [rows][128] bf16 LDS tile
__device__ inline bfrag ld_frag(const unsigned short* buf, int row, int kk, int lhi) {
    int byte = (row * 256 + kk * 64 + lhi * 16) ^ ((row & 7) << 4);
    return *(const bfrag*)((const char*)buf + byte);
}
// barrier draining ONLY LDS ops: global zv prefetch stays in flight across it
__device__ inline void barrier_lgkm() {
    asm volatile("s_waitcnt lgkmcnt(0)\n\ts_barrier" ::: "memory");
}

// ---- kernel 1: prep. blocks 0..156: vocab GEMM, 64 toks/block, W1 col in regs.
//      blocks 157..220: U1/U2/W2 transpose+scale -> bf16 [n][k].
#define PTOK 64
#define VBLK 157
__global__ __launch_bounds__(512) void prep_all(
    const float* __restrict__ emb, const float* __restrict__ W1, const float* __restrict__ b1,
    const float* __restrict__ U1, const float* __restrict__ U2, const float* __restrict__ W2,
    unsigned short* __restrict__ EW1p, unsigned short* __restrict__ U1T,
    unsigned short* __restrict__ U2T, unsigned short* __restrict__ W2T) {
    const int tid = threadIdx.x;
    if (blockIdx.x < VBLK) {
        __shared__ float embs_t[EMB][PTOK + 4];      // transposed, padded
        const int tok0 = blockIdx.x * PTOK;
        for (int i = tid; i < PTOK * EMB; i += 512) {
            int tt = i / EMB, e = i - tt * EMB;
            int gi = tok0 * EMB + i;
            embs_t[e][tt] = (gi < 10000 * EMB) ? emb[gi] : 0.f;
        }
        __syncthreads();
        const int c = tid;                           // z-column = g*128+u
        const int pos = (c & 127) * 4 + (c >> 7);    // interleaved [tok][u*4+g]
        const float scale = ((c >> 7) == 2) ? 2.f * LOG2E : -LOG2E;
        const float bias = b1[c];
        float s[PTOK];
#pragma unroll
        for (int tt = 0; tt < PTOK; tt++) s[tt] = bias;
        // e in chunks of 4; W1 col values held in regs per chunk
        for (int e4 = 0; e4 < EMB / 4; e4++) {
            float w4[4];
#pragma unroll
            for (int i = 0; i < 4; i++) w4[i] = W1[(e4 * 4 + i) * G4 + c];
#pragma unroll
            for (int i = 0; i < 4; i++) {
#pragma unroll
                for (int q = 0; q < PTOK / 4; q++) {
                    float4 ev = *(const float4*)&embs_t[e4 * 4 + i][q * 4];
                    s[q * 4 + 0] += ev.x * w4[i];
                    s[q * 4 + 1] += ev.y * w4[i];
                    s[q * 4 + 2] += ev.z * w4[i];
                    s[q * 4 + 3] += ev.w * w4[i];
                }
            }
        }
#pragma unroll 4
        for (int tt = 0; tt < PTOK; tt++) {
            if (tok0 + tt < 10000)
                EW1p[(size_t)(tok0 + tt) * G4 + pos] = f2bf(s[tt] * scale);
        }
    } else {
#pragma unroll
        for (int r = 0; r < 2; r++) {
            int idx = (blockIdx.x - VBLK) * 1024 + r * 512 + tid;  // 0..65535
            int n = idx >> 7, k = idx & 127;
            const float scale = ((n >> 7) == 2) ? 2.f * LOG2E : -LOG2E;
            U1T[n * 128 + k] = f2bf(U1[k * 512 + n] * scale);
            U2T[n * 128 + k] = f2bf(U2[k * 512 + n] * scale);
            W2T[n * 128 + k] = f2bf(W2[k * 512 + n] * scale);
        }
    }
}

// ---- kernel 2: fused 2-layer LSTM. Weights as MFMA A-operand (z transposed):
//      lane owns (4 consecutive units x 1 row) -> 32B gather, b64 h-stores.
__global__ __launch_bounds__(THR, 2) void lstm_fused(
    const int* __restrict__ tokens, const unsigned short* __restrict__ EW1p,
    const unsigned short* __restrict__ U1T, const unsigned short* __restrict__ U2T,
    const unsigned short* __restrict__ W2T, const float* __restrict__ b2,
    const float* __restrict__ Wd, const float* __restrict__ bd, float* __restrict__ out) {

    __shared__ unsigned short h1b[2][BR * HU];     // h1(s) in buf s&1, swizzled
    __shared__ unsigned short h2b[2][BR * HU];
    __shared__ int toklds[BR * TPAD];
    __shared__ unsigned short w2lds[G4 * HU];      // 131072 B, swizzled rows

    const int tid = threadIdx.x;
    const int w   = tid >> 6;
    const int l   = tid & 63;
    const int llo = l & 15, lhi = l >> 4;
    const int u   = w * 16 + llo;                  // weight-row unit (A-frag lane row)
    const int r0  = blockIdx.x * BR;
    // epilogue mapping: lane owns row=llo, units uw..uw+3
    const int uw  = w * 16 + lhi * 4;
    // write byte offset into h buffer (8B, 4 units)
    const int wb  = (llo * 256 + uw * 2) ^ ((llo & 7) << 4);

    { // stage pre-transposed W2T -> LDS with row-XOR swizzle applied on store
        for (int i = tid; i < G4 * HU / 8; i += THR) {
            int n = i >> 4, c16 = i & 15;
            int byte = (n * 256 + c16 * 16) ^ ((n & 7) << 4);
            *(uint4*)((char*)w2lds + byte) = *(const uint4*)(W2T + n * 128 + c16 * 8);
        }
    }
    for (int i = tid; i < BR * T_SEQ; i += THR) {
        int r = i / T_SEQ, t = i - r * T_SEQ;
        toklds[r * TPAD + t] = tokens[r0 * T_SEQ + i];
    }
    for (int i = tid; i < BR * HU; i += THR) { h2b[0][i] = 0; h2b[1][i] = 0; }

    // recurrent weight slices in registers (MFMA A operands; AGPR-eligible)
    bfrag u1r[4][4], u2r[4][4];
#pragma unroll
    for (int g = 0; g < 4; g++)
#pragma unroll
        for (int kk = 0; kk < 4; kk++) {
            size_t off = (size_t)(g * 128 + u) * 128 + kk * 32 + lhi * 8;
            u1r[g][kk] = *(const bfrag*)(U1T + off);
            u2r[g][kk] = *(const bfrag*)(U2T + off);
        }
    float bb[4];
#pragma unroll
    for (int g = 0; g < 4; g++) bb[g] = b2[g * 128 + u] * ((g == 2) ? 2.f * LOG2E : -LOG2E);

    float c1[4] = {0, 0, 0, 0}, c2[4] = {0, 0, 0, 0};
    uint4 zq0, zq1;   // prefetched x@W1 gathers: 16 shorts = (j,g) j=unit, g=gate

    __syncthreads();

    // ---- prologue: L1(0). h1(-1)=0 -> z1 = gathers only; write h1(0)->h1b[0].
    {
        int tok = toklds[llo * TPAD + 0];
        const char* p = (const char*)(EW1p + (size_t)tok * G4 + w * 64 + lhi * 16);
        zq0 = *(const uint4*)p; zq1 = *(const uint4*)(p + 16);
        float hh[4];
#pragma unroll
        for (int j = 0; j < 4; j++) {
            int d0 = j * 2;   // dwords d0, d0+1 hold gates 0,1 / 2,3 for unit j
            unsigned int da = (j < 2) ? ((unsigned int*)&zq0)[d0 & 3] : ((unsigned int*)&zq1)[d0 & 3];
            unsigned int db = (j < 2) ? ((unsigned int*)&zq0)[(d0 + 1) & 3] : ((unsigned int*)&zq1)[(d0 + 1) & 3];
            float si = sig_p(lo_bf(da)), sf = sig_p(hi_bf(da));
            float tg = tanh_p(lo_bf(db)), so = sig_p(hi_bf(db));
            float cn = sf * c1[j] + si * tg;
            c1[j] = cn;
            hh[j] = so * tanh_r(cn);
        }
        uint2 dv = {cvt_pk_bf16(hh[0], hh[1]), cvt_pk_bf16(hh[2], hh[3])};
        *(uint2*)((char*)h1b[0] + wb) = dv;
        // prefetch gathers for s=1
        tok = toklds[llo * TPAD + 1];
        p = (const char*)(EW1p + (size_t)tok * G4 + w * 64 + lhi * 16);
        zq0 = *(const uint4*)p; zq1 = *(const uint4*)(p + 16);
    }
    __syncthreads();

    // phase(sn, bufs): step s = { L1(s); L2(s-1) }; sn = next prefetch step
    auto phase = [&](int sn, const unsigned short* h1p, const unsigned short* h2p,
                     unsigned short* h1n, unsigned short* h2n) {
        // (1) h-frag LDS reads (MFMA B operands)
        bfrag b1f[4], b2f[4];
#pragma unroll
        for (int kk = 0; kk < 4; kk++) b1f[kk] = ld_frag(h1p, llo, kk, lhi);
#pragma unroll
        for (int kk = 0; kk < 4; kk++) b2f[kk] = ld_frag(h2p, llo, kk, lhi);
        // (2) acc1 init from prefetched gathers (z1 = x@W1+b1, pre-scaled)
        f32x4 acc1[4];
#pragma unroll
        for (int j = 0; j < 4; j++) {
            unsigned int da = (j < 2) ? ((unsigned int*)&zq0)[(j * 2) & 3] : ((unsigned int*)&zq1)[(j * 2) & 3];
            unsigned int db = (j < 2) ? ((unsigned int*)&zq0)[(j * 2 + 1) & 3] : ((unsigned int*)&zq1)[(j * 2 + 1) & 3];
            acc1[0][j] = lo_bf(da); acc1[1][j] = hi_bf(da);
            acc1[2][j] = lo_bf(db); acc1[3][j] = hi_bf(db);
        }
        // (3) prefetch next step's gathers (span the lgkm-only barrier)
        {
            int tok = toklds[llo * TPAD + sn];
            const char* p = (const char*)(EW1p + (size_t)tok * G4 + w * 64 + lhi * 16);
            zq0 = *(const uint4*)p; zq1 = *(const uint4*)(p + 16);
        }
        // (4) L1 MFMA: acc1 += U1 x h1(s-1)   (weights as A)
#pragma unroll
        for (int g = 0; g < 4; g++)
#pragma unroll
            for (int kk = 0; kk < 4; kk++)
                acc1[g] = __builtin_amdgcn_mfma_f32_16x16x32_bf16(u1r[g][kk], b1f[kk], acc1[g], 0, 0, 0);
        // (5) acc2 init + U2 MFMA
        f32x4 acc2[4];
#pragma unroll
        for (int g = 0; g < 4; g++) acc2[g] = (f32x4){bb[g], bb[g], bb[g], bb[g]};
#pragma unroll
        for (int kk = 0; kk < 4; kk++)
#pragma unroll
            for (int g = 0; g < 4; g++)
                acc2[g] = __builtin_amdgcn_mfma_f32_16x16x32_bf16(u2r[g][kk], b2f[kk], acc2[g], 0, 0, 0);
        // (6) L1 epilogue -> h1n (b64 store of 4 packed units)
        {
            float hh[4];
#pragma unroll
            for (int j = 0; j < 4; j++) {
                float si = sig_p(acc1[0][j]), sf = sig_p(acc1[1][j]);
                float tg = tanh_p(acc1[2][j]), so = sig_p(acc1[3][j]);
                float cn = sf * c1[j] + si * tg;
                c1[j] = cn;
                hh[j] = so * tanh_r(cn);
            }
            uint2 dv = {cvt_pk_bf16(hh[0], hh[1]), cvt_pk_bf16(hh[2], hh[3])};
            *(uint2*)((char*)h1n + wb) = dv;
        }
        // (7) W2 MFMAs (weights as A, streamed from LDS)
#pragma unroll
        for (int g = 0; g < 4; g++) {
            bfrag wf[4];
#pragma unroll
            for (int kk = 0; kk < 4; kk++) wf[kk] = ld_frag(w2lds, g * 128 + u, kk, lhi);
#pragma unroll
            for (int kk = 0; kk < 4; kk++)
                acc2[g] = __builtin_amdgcn_mfma_f32_16x16x32_bf16(wf[kk], b1f[kk], acc2[g], 0, 0, 0);
        }
        // (8) L2 epilogue -> h2n
        {
            float hh[4];
#pragma unroll
            for (int j = 0; j < 4; j++) {
                float si = sig_p(acc2[0][j]), sf = sig_p(acc2[1][j]);
                float tg = tanh_p(acc2[2][j]), so = sig_p(acc2[3][j]);
                float cn = sf * c2[j] + si * tg;
                c2[j] = cn;
                hh[j] = so * tanh_r(cn);
            }
            uint2 dv = {cvt_pk_bf16(hh[0], hh[1]), cvt_pk_bf16(hh[2], hh[3])};
            *(uint2*)((char*)h2n + wb) = dv;
        }
        barrier_lgkm();
    };

    // phases s=1..79
    phase(2, h1b[0], h2b[1], h1b[1], h2b[0]);                       // s=1
#pragma unroll 1
    for (int s = 2; s < T_SEQ - 1; s += 2) {
        phase(s + 1, h1b[1], h2b[0], h1b[0], h2b[1]);               // even s
        phase((s + 2 < T_SEQ) ? s + 2 : T_SEQ - 1,
              h1b[0], h2b[1], h1b[1], h2b[0]);                      // odd s+1
    }

    // ---- tail: L2(79). reads h1(79)=h1b[1], h2(78)=h2b[0]; writes h2(79)->h2b[1]
    {
        bfrag b1f[4], b2f[4];
#pragma unroll
        for (int kk = 0; kk < 4; kk++) b1f[kk] = ld_frag(h1b[1], llo, kk, lhi);
#pragma unroll
        for (int kk = 0; kk < 4; kk++) b2f[kk] = ld_frag(h2b[0], llo, kk, lhi);
        f32x4 acc2[4];
#pragma unroll
        for (int g = 0; g < 4; g++) acc2[g] = (f32x4){bb[g], bb[g], bb[g], bb[g]};
#pragma unroll
        for (int kk = 0; kk < 4; kk++)
#pragma unroll
            for (int g = 0; g < 4; g++)
                acc2[g] = __builtin_amdgcn_mfma_f32_16x16x32_bf16(u2r[g][kk], b2f[kk], acc2[g], 0, 0, 0);
#pragma unroll
        for (int g = 0; g < 4; g++) {
            bfrag wf[4];
#pragma unroll
            for (int kk = 0; kk < 4; kk++) wf[kk] = ld_frag(w2lds, g * 128 + u, kk, lhi);
#pragma unroll
            for (int kk = 0; kk < 4; kk++)
                acc2[g] = __builtin_amdgcn_mfma_f32_16x16x32_bf16(wf[kk], b1f[kk], acc2[g], 0, 0, 0);
        }
        float hh[4];
#pragma unroll
        for (int j = 0; j < 4; j++) {
            float si = sig_p(acc2[0][j]), sf = sig_p(acc2[1][j]);
            float tg = tanh_p(acc2[2][j]), so = sig_p(acc2[3][j]);
            float cn = sf * c2[j] + si * tg;
            c2[j] = cn;
            hh[j] = so * tanh_r(cn);
        }
        uint2 dv = {cvt_pk_bf16(hh[0], hh[1]), cvt_pk_bf16(hh[2], hh[3])};
        *(uint2*)((char*)h2b[1] + wb) = dv;
    }
    __syncthreads();

    // ---- dense head: out = sigmoid(h2(79) @ Wd + bd); h2(79) in h2b[1]
    if (w == 0) {
        int r = l >> 2, q = l & 3;
        float s = 0.f;
        for (int k = q * 32; k < q * 32 + 32; k++) {
            int byte = (r * 256 + k * 2) ^ ((r & 7) << 4);
            s += lo_bf(*(const unsigned short*)((const char*)h2b[1] + byte)) * Wd[k];
        }
        s += __shfl_xor(s, 1, 64);
        s += __shfl_xor(s, 2, 64);
        if (q == 0) out[r0 + r] = sig_r(s + bd[0]);
    }
}

extern "C" void kernel_launch(void* const* d_in, const int* in_sizes, int n_in,
                              void* d_out, int out_size, void* d_ws, size_t ws_size,
                              hipStream_t stream) {
    const int*   tokens = (const int*)  d_in[0];
    const float* emb    = (const float*)d_in[1];
    const float* W1     = (const float*)d_in[2];
    const float* U1     = (const float*)d_in[3];
    const float* b1     = (const float*)d_in[4];
    const float* W2     = (const float*)d_in[5];
    const float* U2     = (const float*)d_in[6];
    const float* b2     = (const float*)d_in[7];
    const float* Wd     = (const float*)d_in[8];
    const float* bd     = (const float*)d_in[9];
    float* out = (float*)d_out;

    char* ws = (char*)d_ws;
    unsigned short* EW1p = (unsigned short*)(ws + OFF_EW1P);
    unsigned short* U1T  = (unsigned short*)(ws + OFF_U1T);
    unsigned short* U2T  = (unsigned short*)(ws + OFF_U2T);
    unsigned short* W2T  = (unsigned short*)(ws + OFF_W2T);

    prep_all<<<VBLK + 64, 512, 0, stream>>>(emb, W1, b1, U1, U2, W2, EW1p, U1T, U2T, W2T);
    lstm_fused<<<256, THR, 0, stream>>>(tokens, EW1p, U1T, U2T, W2T, b2, Wd, bd, out);
}